// Round 22
// baseline (1502.613 us; speedup 1.0000x reference)
//
#include <hip/hip_runtime.h>
#include <hip/hip_bf16.h>

constexpr int N1 = 4096;  // V rows
constexpr int D1 = 1024;  // visual dim
constexpr int N2 = 4096;  // X rows
constexpr int D2 = 4096;  // text dim

#define FNEG  (-3.402823466e+38f)
#define IDX_INF 0x7FFFFFFF
#define NCHUNK 32
#define CPR (NCHUNK * 6)      // 192 candidates per row
#define FCAP 1024             // flagged-row capacity
#define ZCH 8                 // z rows per register chunk
#define ZB 32                 // z-group blocks
#define CERT_TH 2.0e-4f       // certification threshold

using s16x8 = __attribute__((ext_vector_type(8))) short;
using f32x4 = __attribute__((ext_vector_type(4))) float;

static __device__ __forceinline__ unsigned short f2bf(float x) {
    unsigned int u = __float_as_uint(x);
    unsigned int r = (u + 0x7FFFu + ((u >> 16) & 1u)) >> 16;  // RNE
    return (unsigned short)r;
}
static __device__ __forceinline__ float bf2f(unsigned short v) {
    return __uint_as_float((unsigned)v << 16);
}
static __device__ __forceinline__ void splitbf(float x, unsigned short& h,
                                               unsigned short& l) {
    unsigned short hh = f2bf(x);
    float r = x - __uint_as_float((unsigned)hh << 16);
    h = hh; l = f2bf(r);
}
static __device__ __forceinline__ int swz(int row, int g) {
    return row * 32 + ((g ^ (row & 3)) << 3);
}

// stage 128x32 f32 tile -> split bf16 LDS (on-the-fly split; mfmaZ only)
static __device__ __forceinline__ void stageF32(const float* src, int ld,
    int rowbase, int k0, unsigned short* H, unsigned short* L, int tid)
{
    const int r = tid >> 1, half = tid & 1;
    const float* p = src + (size_t)(rowbase + r) * ld + k0 + half * 16;
#pragma unroll
    for (int gg = 0; gg < 2; ++gg) {
        const int g = half * 2 + gg;
        float4 v0 = *(const float4*)(p + gg * 8);
        float4 v1 = *(const float4*)(p + gg * 8 + 4);
        float xs[8] = {v0.x, v0.y, v0.z, v0.w, v1.x, v1.y, v1.z, v1.w};
        s16x8 hv, lv;
#pragma unroll
        for (int e = 0; e < 8; ++e) {
            unsigned short h, l; splitbf(xs[e], h, l);
            hv[e] = (short)h; lv[e] = (short)l;
        }
        const int a = swz(r, g);
        *(s16x8*)&H[a] = hv;
        *(s16x8*)&L[a] = lv;
    }
}

// -------- global_load_lds staging of 128x32 pre-split bf16 tiles ----------
static __device__ __forceinline__ void gl_lds16(const void* g, void* l)
{
    __builtin_amdgcn_global_load_lds(
        (const __attribute__((address_space(1))) void*)g,
        (__attribute__((address_space(3))) void*)l, 16, 0, 0);
}

static __device__ __forceinline__ void stageSplitGL(const unsigned short* Hs,
    const unsigned short* Ls, int ld, int rowbase, int k0,
    unsigned short* H, unsigned short* L, int lane, int w)
{
#pragma unroll
    for (int t = 0; t < 2; ++t) {
        const int chunk = w * 128 + t * 64 + lane;   // 0..511 (16B units)
        const int row = chunk >> 2;
        const int gp  = chunk & 3;                   // dest group
        const int g   = gp ^ (row & 3);              // source group (involution)
        const unsigned short* sh =
            Hs + (size_t)(rowbase + row) * ld + k0 + g * 8;
        const unsigned short* sl =
            Ls + (size_t)(rowbase + row) * ld + k0 + g * 8;
        unsigned short* dh = H + (size_t)(w * 128 + t * 64) * 8;
        unsigned short* dl = L + (size_t)(w * 128 + t * 64) * 8;
        gl_lds16(sh, dh);
        gl_lds16(sl, dl);
    }
}

// stage Wv transposed from PRE-SPLIT pair (scatter; mfmaZ only)
static __device__ __forceinline__ void stageWvTpre(const unsigned short* Wh,
    const unsigned short* Wl, int k0, int tn,
    unsigned short* H, unsigned short* L, int tid)
{
    const int kk = tid >> 3, cg = tid & 7;
    const int g = kk >> 3, idx = kk & 7;
    const unsigned short* ph = Wh + (size_t)(k0 + kk) * D1 + tn + cg * 16;
    const unsigned short* pl = Wl + (size_t)(k0 + kk) * D1 + tn + cg * 16;
#pragma unroll
    for (int q = 0; q < 4; ++q) {
        ushort4 vh = *(const ushort4*)(ph + q * 4);
        ushort4 vl = *(const ushort4*)(pl + q * 4);
        unsigned short hs[4] = {vh.x, vh.y, vh.z, vh.w};
        unsigned short ls[4] = {vl.x, vl.y, vl.z, vl.w};
#pragma unroll
        for (int e = 0; e < 4; ++e) {
            const int cc = cg * 16 + q * 4 + e;
            const int a = cc * 32 + ((g ^ (cc & 3)) << 3) + idx;
            H[a] = hs[e]; L[a] = ls[e];
        }
    }
}

static __device__ __forceinline__ s16x8 fragRead(const unsigned short* B,
                                                 int rowbase, int lane)
{
    const int row = rowbase + (lane & 15);
    const int g = lane >> 4;
    return *(const s16x8*)&B[row * 32 + ((g ^ (row & 3)) << 3)];
}

#define MFMA3(ACC, AH, AL, BH, BL)                                          \
    ACC = __builtin_amdgcn_mfma_f32_16x16x32_bf16(AH, BH, ACC, 0, 0, 0);    \
    ACC = __builtin_amdgcn_mfma_f32_16x16x32_bf16(AH, BL, ACC, 0, 0, 0);    \
    ACC = __builtin_amdgcn_mfma_f32_16x16x32_bf16(AL, BH, ACC, 0, 0, 0);

static __device__ __forceinline__ void top6f(float v, int i, float* vv, int* ii)
{
#pragma unroll
    for (int s = 0; s < 6; ++s) {
        if (v > vv[s]) {
#pragma unroll
            for (int t = 5; t > s; --t) { vv[t] = vv[t-1]; ii[t] = ii[t-1]; }
            vv[s] = v; ii[s] = i;
            break;
        }
    }
}

// ---------------------------------------------------------------------------
__global__ __launch_bounds__(256)
void kDetect(const float* c1, const float* c2, int* flags, int* flagCnt)
{
    __shared__ float red[256];
    float d = 0.f;
    for (int i = threadIdx.x; i < 4096; i += 256) {
        float a = c1[i], b = c2[i];
        d += a * a - b * b;
    }
    red[threadIdx.x] = d;
    __syncthreads();
    for (int st = 128; st > 0; st >>= 1) {
        if (threadIdx.x < st) red[threadIdx.x] += red[threadIdx.x + st];
        __syncthreads();
    }
    if (threadIdx.x == 0) {
        flags[0] = (red[0] < 0.f) ? 1 : 0;
        flagCnt[0] = 0;
    }
}

__global__ __launch_bounds__(256)
void kSplit(const float* src, unsigned short* h, unsigned short* l, int n4)
{
    int i = blockIdx.x * 256 + threadIdx.x;
    if (i >= n4) return;
    float4 v = *(const float4*)(src + (size_t)i * 4);
    float xs[4] = {v.x, v.y, v.z, v.w};
    ushort4 hv, lv;
    unsigned short hh, ll;
    splitbf(xs[0], hh, ll); hv.x = hh; lv.x = ll;
    splitbf(xs[1], hh, ll); hv.y = hh; lv.y = ll;
    splitbf(xs[2], hh, ll); hv.z = hh; lv.z = ll;
    splitbf(xs[3], hh, ll); hv.w = hh; lv.w = ll;
    *(ushort4*)(h + (size_t)i * 4) = hv;
    *(ushort4*)(l + (size_t)i * 4) = lv;
}

// sXF (f32) + sXD (f64): sum_n X[i,n]*bv[n]
__global__ __launch_bounds__(256)
void kSvec(const float* X, const float* bv, float* sXF, double* sXD)
{
    __shared__ double red[256];
    const int row = blockIdx.x;
    double s = 0.0;
    for (int n = threadIdx.x; n < D2; n += 256)
        s += (double)X[(size_t)row * D2 + n] * (double)bv[n];
    red[threadIdx.x] = s;
    __syncthreads();
    for (int st = 128; st > 0; st >>= 1) {
        if (threadIdx.x < st) red[threadIdx.x] += red[threadIdx.x + st];
        __syncthreads();
    }
    if (threadIdx.x == 0) { sXF[row] = (float)red[0]; sXD[row] = red[0]; }
}

// ---------------------------------------------------------------------------
// kNormMfma: ||Vp_j||^2 partials + bf16 Vp store. 2-PHASE double-buffered.
__global__ __launch_bounds__(256)
void kNormMfma(const unsigned short* c1h, const unsigned short* c1l,
               const unsigned short* c2h, const unsigned short* c2l,
               const float* bv, const int* flags, float* partial,
               unsigned short* Vph)
{
    const unsigned short* Vh  = flags[0] ? c2h : c1h;
    const unsigned short* Vl  = flags[0] ? c2l : c1l;
    const unsigned short* Wvh = flags[0] ? c1h : c2h;
    const unsigned short* Wvl = flags[0] ? c1l : c2l;
    __shared__ __align__(16) char pool[65536];   // 2 x 32KB buffers
    __shared__ float partH[128][2];
    const int tid = threadIdx.x;
    const int lane = tid & 63, w = tid >> 6;
    const int wr = w >> 1, wc = w & 1;
    const int tm = blockIdx.y * 128;
    const int tn = blockIdx.x * 128;

    f32x4 acc[4][4];
#pragma unroll
    for (int i = 0; i < 4; ++i)
#pragma unroll
        for (int j = 0; j < 4; ++j) acc[i][j] = (f32x4){0.f, 0.f, 0.f, 0.f};

    {   // prologue: stage k0=0 into buf0
        unsigned short* B0 = (unsigned short*)pool;
        stageSplitGL(Vh,  Vl,  D1, tm, 0, B0,        B0 + 4096,  lane, w);
        stageSplitGL(Wvh, Wvl, D1, tn, 0, B0 + 8192, B0 + 12288, lane, w);
    }
    __syncthreads();

    for (int k0 = 0; k0 < D1; k0 += 32) {
        const int cur = (k0 >> 5) & 1;
        unsigned short* CB = (unsigned short*)(pool + cur * 32768);
        if (k0 + 32 < D1) {
            unsigned short* NB = (unsigned short*)(pool + (cur ^ 1) * 32768);
            stageSplitGL(Vh,  Vl,  D1, tm, k0 + 32, NB,        NB + 4096,
                         lane, w);
            stageSplitGL(Wvh, Wvl, D1, tn, k0 + 32, NB + 8192, NB + 12288,
                         lane, w);
        }
        s16x8 ah[4], al[4], bh[4], bl[4];
#pragma unroll
        for (int f = 0; f < 4; ++f) {
            ah[f] = fragRead(CB,         wr * 64 + f * 16, lane);
            al[f] = fragRead(CB + 4096,  wr * 64 + f * 16, lane);
            bh[f] = fragRead(CB + 8192,  wc * 64 + f * 16, lane);
            bl[f] = fragRead(CB + 12288, wc * 64 + f * 16, lane);
        }
#pragma unroll
        for (int fm = 0; fm < 4; ++fm)
#pragma unroll
            for (int fn = 0; fn < 4; ++fn) {
                MFMA3(acc[fm][fn], ah[fm], al[fm], bh[fn], bl[fn]);
            }
        __syncthreads();   // drains prefetch (vmcnt) + guards buffer reuse
    }

    float bvv[4];
#pragma unroll
    for (int fn = 0; fn < 4; ++fn)
        bvv[fn] = bv[tn + wc * 64 + fn * 16 + (lane & 15)];
#pragma unroll
    for (int fm = 0; fm < 4; ++fm)
#pragma unroll
        for (int r = 0; r < 4; ++r) {
            const int lrow = wr * 64 + fm * 16 + (lane >> 4) * 4 + r;
            float rs = 0.f;
#pragma unroll
            for (int fn = 0; fn < 4; ++fn) {
                float v = acc[fm][fn][r] + bvv[fn];
                Vph[(size_t)(tm + lrow) * D2 +
                    (tn + wc * 64 + fn * 16 + (lane & 15))] = f2bf(v);
                rs += v * v;
            }
            rs += __shfl_xor(rs, 1, 64);
            rs += __shfl_xor(rs, 2, 64);
            rs += __shfl_xor(rs, 4, 64);
            rs += __shfl_xor(rs, 8, 64);
            if ((lane & 15) == 0) partH[lrow][wc] = rs;
        }
    __syncthreads();
    if (tid < 128)
        partial[(size_t)(tm + tid) * 32 + blockIdx.x] =
            partH[tid][0] + partH[tid][1];
}

// kInv: f64 sum of strip partials -> invnD (f64) + invnF (f32)
__global__ __launch_bounds__(256)
void kInv(const float* partial, float* invnF, double* invnD)
{
    int j = blockIdx.x * 256 + threadIdx.x;
    double s = 0.0;
    for (int cb = 0; cb < 32; ++cb) s += (double)partial[(size_t)j * 32 + cb];
    double iv = 1.0 / (sqrt(s) + 1e-8);
    invnD[j] = iv;
    invnF[j] = (float)iv;
}

// ---------------------------------------------------------------------------
// mfmaZ: Z = X @ Wv -> pre-split Zh/Zl
__global__ __launch_bounds__(256)
void mfmaZ(const float* X,
           const unsigned short* c1h, const unsigned short* c1l,
           const unsigned short* c2h, const unsigned short* c2l,
           const int* flags, unsigned short* Zh, unsigned short* Zl)
{
    const unsigned short* Wvh = flags[0] ? c1h : c2h;
    const unsigned short* Wvl = flags[0] ? c1l : c2l;
    __shared__ unsigned short AH[4096], AL[4096], BH[4096], BL[4096];
    const int tid = threadIdx.x;
    const int lane = tid & 63, w = tid >> 6;
    const int wr = w >> 1, wc = w & 1;
    const int tm = blockIdx.y * 128;
    const int tn = blockIdx.x * 128;

    f32x4 acc[4][4];
#pragma unroll
    for (int i = 0; i < 4; ++i)
#pragma unroll
        for (int j = 0; j < 4; ++j) acc[i][j] = (f32x4){0.f, 0.f, 0.f, 0.f};

    for (int k0 = 0; k0 < D2; k0 += 32) {
        stageF32(X, D2, tm, k0, AH, AL, tid);
        stageWvTpre(Wvh, Wvl, k0, tn, BH, BL, tid);
        __syncthreads();
        s16x8 ah[4], al[4], bh[4], bl[4];
#pragma unroll
        for (int f = 0; f < 4; ++f) {
            ah[f] = fragRead(AH, wr * 64 + f * 16, lane);
            al[f] = fragRead(AL, wr * 64 + f * 16, lane);
            bh[f] = fragRead(BH, wc * 64 + f * 16, lane);
            bl[f] = fragRead(BL, wc * 64 + f * 16, lane);
        }
#pragma unroll
        for (int fm = 0; fm < 4; ++fm)
#pragma unroll
            for (int fn = 0; fn < 4; ++fn) {
                MFMA3(acc[fm][fn], ah[fm], al[fm], bh[fn], bl[fn]);
            }
        __syncthreads();
    }
#pragma unroll
    for (int fm = 0; fm < 4; ++fm)
#pragma unroll
        for (int fn = 0; fn < 4; ++fn)
#pragma unroll
            for (int r = 0; r < 4; ++r) {
                int row = tm + wr * 64 + fm * 16 + (lane >> 4) * 4 + r;
                int col = tn + wc * 64 + fn * 16 + (lane & 15);
                unsigned short h, l;
                splitbf(acc[fm][fn][r], h, l);
                size_t o = (size_t)row * D1 + col;
                Zh[o] = h; Zl[o] = l;
            }
}

// ---------------------------------------------------------------------------
// mfmaS: scores = Z @ V^T + per-chunk top-6. 2-PHASE double-buffered K-loop.
__global__ __launch_bounds__(256)
void mfmaS(const unsigned short* Zh, const unsigned short* Zl,
           const unsigned short* c1h, const unsigned short* c1l,
           const unsigned short* c2h, const unsigned short* c2l,
           const float* invnF, const float* sXF, const int* flags,
           float* candV, int* candI)
{
    const unsigned short* Vh = flags[0] ? c2h : c1h;
    const unsigned short* Vl = flags[0] ? c2l : c1l;
    __shared__ __align__(16) char pool[65536];   // 2 x 32KB; epilogue overlay
    float* Ct   = (float*)pool;
    float* pv   = (float*)(pool + 33792);
    int*   pi   = (int*)  (pool + 36864);
    float* invs = (float*)(pool + 39936);

    const int tid = threadIdx.x;
    const int lane = tid & 63, w = tid >> 6;
    const int wr = w >> 1, wc = w & 1;
    const int tm = blockIdx.y * 128;
    const int tn = blockIdx.x * 128;

    f32x4 acc[4][4];
#pragma unroll
    for (int i = 0; i < 4; ++i)
#pragma unroll
        for (int j = 0; j < 4; ++j) acc[i][j] = (f32x4){0.f, 0.f, 0.f, 0.f};

    {   // prologue
        unsigned short* B0 = (unsigned short*)pool;
        stageSplitGL(Zh, Zl, D1, tm, 0, B0,        B0 + 4096,  lane, w);
        stageSplitGL(Vh, Vl, D1, tn, 0, B0 + 8192, B0 + 12288, lane, w);
    }
    __syncthreads();

    for (int k0 = 0; k0 < D1; k0 += 32) {
        const int cur = (k0 >> 5) & 1;
        unsigned short* CB = (unsigned short*)(pool + cur * 32768);
        if (k0 + 32 < D1) {
            unsigned short* NB = (unsigned short*)(pool + (cur ^ 1) * 32768);
            stageSplitGL(Zh, Zl, D1, tm, k0 + 32, NB,        NB + 4096,
                         lane, w);
            stageSplitGL(Vh, Vl, D1, tn, k0 + 32, NB + 8192, NB + 12288,
                         lane, w);
        }
        s16x8 ah[4], al[4], bh[4], bl[4];
#pragma unroll
        for (int f = 0; f < 4; ++f) {
            ah[f] = fragRead(CB,         wr * 64 + f * 16, lane);
            al[f] = fragRead(CB + 4096,  wr * 64 + f * 16, lane);
            bh[f] = fragRead(CB + 8192,  wc * 64 + f * 16, lane);
            bl[f] = fragRead(CB + 12288, wc * 64 + f * 16, lane);
        }
#pragma unroll
        for (int fm = 0; fm < 4; ++fm)
#pragma unroll
            for (int fn = 0; fn < 4; ++fn) {
                MFMA3(acc[fm][fn], ah[fm], al[fm], bh[fn], bl[fn]);
            }
        __syncthreads();
    }

    if (tid < 128) invs[tid] = invnF[tn + tid];
    for (int h = 0; h < 2; ++h) {
        __syncthreads();
        if (wr == h) {
#pragma unroll
            for (int fm = 0; fm < 4; ++fm)
#pragma unroll
                for (int fn = 0; fn < 4; ++fn)
#pragma unroll
                    for (int r = 0; r < 4; ++r) {
                        int lr = fm * 16 + (lane >> 4) * 4 + r;
                        int c  = wc * 64 + fn * 16 + (lane & 15);
                        Ct[lr * 132 + c] = acc[fm][fn][r];
                    }
        }
        __syncthreads();
        if (tid < 128) {
            int r = tid >> 1, seg = tid & 1;
            float sxf = sXF[tm + h * 64 + r];
            float vv[6]; int ii[6];
#pragma unroll
            for (int s = 0; s < 6; ++s) { vv[s] = FNEG; ii[s] = IDX_INF; }
            for (int cc = 0; cc < 64; ++cc) {
                int c = seg * 64 + cc;
                float v = (Ct[r * 132 + c] + sxf) * invs[c];
                top6f(v, tn + c, vv, ii);
            }
#pragma unroll
            for (int s = 0; s < 6; ++s) {
                pv[(r * 2 + seg) * 6 + s] = vv[s];
                pi[(r * 2 + seg) * 6 + s] = ii[s];
            }
        }
        __syncthreads();
        if (tid < 64) {
            float vv[6]; int ii[6];
#pragma unroll
            for (int s = 0; s < 6; ++s) { vv[s] = FNEG; ii[s] = IDX_INF; }
            for (int seg = 0; seg < 2; ++seg)
                for (int s = 0; s < 6; ++s)
                    top6f(pv[(tid * 2 + seg) * 6 + s],
                          pi[(tid * 2 + seg) * 6 + s], vv, ii);
            int row = tm + h * 64 + tid;
#pragma unroll
            for (int s = 0; s < 6; ++s) {
                candV[(size_t)row * CPR + blockIdx.x * 6 + s] = vv[s];
                candI[(size_t)row * CPR + blockIdx.x * 6 + s] = ii[s];
            }
        }
    }
}

// ---------------------------------------------------------------------------
__global__ __launch_bounds__(64)
void kMergeCert(const float* candV, const int* candI, int* tidx,
                int* flagCnt, int* flagRow, int* flagCand)
{
    if (threadIdx.x != 0) return;
    const int row = blockIdx.x;
    float vv[6]; int ii[6];
    for (int s = 0; s < 6; ++s) { vv[s] = FNEG; ii[s] = IDX_INF; }
    for (int c = 0; c < CPR; ++c)
        top6f(candV[(size_t)row * CPR + c], candI[(size_t)row * CPR + c],
              vv, ii);
    tidx[row * 3 + 0] = ii[0];
    tidx[row * 3 + 1] = ii[1];
    tidx[row * 3 + 2] = ii[2];
    bool cert = (vv[0] - vv[1] > CERT_TH) &&
                (vv[1] - vv[2] > CERT_TH) &&
                (vv[2] - vv[3] > CERT_TH);
    if (!cert) {
        int idx = atomicAdd(flagCnt, 1);
        if (idx < FCAP) {
            flagRow[idx] = row;
            for (int s = 0; s < 6; ++s) flagCand[idx * 6 + s] = ii[s];
        }
    }
}

// ---------------------------------------------------------------------------
// kZx v2: exact f64 Zx rows for flagged rows, column-parallel.
// Grid (8 cc, 32 zb), 128 threads. Thread owns column c = cc*128 + tid.
// Z rows processed in register chunks of ZCH=8; X rows staged per n-chunk in
// LDS (broadcast reads). Per-(z,c) sum order: n ascending (== v1, bitwise).
// bid%8 == cc -> same-cc blocks share one XCD; 2MB Wv panel is L2-resident.
__global__ __launch_bounds__(128)
void kZx(const int* flagCnt, const int* flagRow,
         const float* c1, const float* c2, const int* flags,
         const float* X, double* Zx)
{
    const float* Wv = flags[0] ? c1 : c2;
    const int nact = min(flagCnt[0], FCAP);
    const int cc = blockIdx.x;        // 0..7
    const int zb = blockIdx.y;        // 0..31
    const int tid = threadIdx.x;      // 0..127
    const int c = cc * 128 + tid;
    __shared__ float Xs[ZCH][1024];   // 32 KB
    __shared__ int   rows[ZCH];

    for (int z0 = zb * ZCH; z0 < nact; z0 += ZB * ZCH) {
        const int na = min(ZCH, nact - z0);
        __syncthreads();              // guard rows/Xs reuse
        if (tid < ZCH)
            rows[tid] = flagRow[z0 + min(tid, na - 1)];
        __syncthreads();

        double acc[ZCH];
#pragma unroll
        for (int zz = 0; zz < ZCH; ++zz) acc[zz] = 0.0;

        for (int n0 = 0; n0 < D2; n0 += 1024) {
            __syncthreads();          // guard Xs overwrite vs prior reads
            // stage ZCH x 1024 floats: 8192 elems, 128 thr x 16 (4x float4)
            for (int idx = tid * 4; idx < ZCH * 1024; idx += 128 * 4) {
                const int zz = idx >> 10, i = idx & 1023;
                *(float4*)&Xs[zz][i] =
                    *(const float4*)(X + (size_t)rows[zz] * D2 + n0 + i);
            }
            __syncthreads();
#pragma unroll 4
            for (int i = 0; i < 1024; ++i) {
                const double wvd = (double)Wv[(size_t)(n0 + i) * D1 + c];
#pragma unroll
                for (int zz = 0; zz < ZCH; ++zz)
                    acc[zz] = fma((double)Xs[zz][i], wvd, acc[zz]);
            }
        }
#pragma unroll
        for (int zz = 0; zz < ZCH; ++zz)
            if (zz < na)
                Zx[(size_t)(z0 + zz) * D1 + c] = acc[zz];
    }
}

// ---------------------------------------------------------------------------
// kScore6: exact refine. s = (Zx_z . V_j + sXD_row) * invnD_j; sort; tidx.
__global__ __launch_bounds__(64)
void kScore6(const int* flagCnt, const int* flagRow, const int* flagCand,
             const double* Zx, const float* c1, const float* c2,
             const int* flags, const double* sXD, const double* invnD,
             int* tidx)
{
    const int z = blockIdx.x;
    if (z >= flagCnt[0] || z >= FCAP) return;
    const float* V = flags[0] ? c2 : c1;
    const int lane = threadIdx.x;

    double zr[16];
#pragma unroll
    for (int t = 0; t < 16; ++t)
        zr[t] = Zx[(size_t)z * D1 + t * 64 + lane];

    double sc[6]; int js[6];
    for (int s = 0; s < 6; ++s) {
        js[s] = flagCand[z * 6 + s];
        const float* vr = V + (size_t)js[s] * D1;
        double d = 0.0;
#pragma unroll
        for (int t = 0; t < 16; ++t)
            d = fma(zr[t], (double)vr[t * 64 + lane], d);
#pragma unroll
        for (int off = 1; off < 64; off <<= 1)
            d += __shfl_xor(d, off, 64);
        sc[s] = d;
    }
    if (lane == 0) {
        const int row = flagRow[z];
        const double sx = sXD[row];
        for (int s = 0; s < 6; ++s)
            sc[s] = (sc[s] + sx) * invnD[js[s]];
        int ord[6] = {0, 1, 2, 3, 4, 5};
        for (int a = 0; a < 5; ++a)
            for (int b = a + 1; b < 6; ++b) {
                bool swp = (sc[ord[b]] > sc[ord[a]]) ||
                           (sc[ord[b]] == sc[ord[a]] &&
                            js[ord[b]] < js[ord[a]]);
                if (swp) { int t = ord[a]; ord[a] = ord[b]; ord[b] = t; }
            }
        tidx[row * 3 + 0] = js[ord[0]];
        tidx[row * 3 + 1] = js[ord[1]];
        tidx[row * 3 + 2] = js[ord[2]];
    }
}

// ---------------------------------------------------------------------------
// kGatherVa: out[row,:] = w0*Vp[i0,:] + w1*Vp[i1,:] + w2*Vp[i2,:] + bf
__global__ __launch_bounds__(256)
void kGatherVa(const unsigned short* Vph, const int* tidx,
               const float* Wf, const float* bfp, float* outVa)
{
    const int row = blockIdx.x;
    const int i0 = tidx[row*3+0], i1 = tidx[row*3+1], i2 = tidx[row*3+2];
    const float w0 = Wf[0], w1 = Wf[1], w2 = Wf[2], b = bfp[0];
    const unsigned short* p0 = Vph + (size_t)i0 * D2;
    const unsigned short* p1 = Vph + (size_t)i1 * D2;
    const unsigned short* p2 = Vph + (size_t)i2 * D2;
    float* o = outVa + (size_t)row * D2;
    for (int c = threadIdx.x * 8; c < D2; c += 256 * 8) {
        s16x8 a = *(const s16x8*)(p0 + c);
        s16x8 d = *(const s16x8*)(p1 + c);
        s16x8 e = *(const s16x8*)(p2 + c);
        float out[8];
#pragma unroll
        for (int t = 0; t < 8; ++t)
            out[t] = w0 * bf2f((unsigned short)a[t]) +
                     w1 * bf2f((unsigned short)d[t]) +
                     w2 * bf2f((unsigned short)e[t]) + b;
        *(float4*)(o + c)     = *(float4*)&out[0];
        *(float4*)(o + c + 4) = *(float4*)&out[4];
    }
}

// ---------------------------------------------------------------------------
extern "C" void kernel_launch(void* const* d_in, const int* in_sizes, int n_in,
                              void* d_out, int out_size, void* d_ws, size_t ws_size,
                              hipStream_t stream)
{
    const float *c1 = nullptr, *c2 = nullptr, *X = nullptr;
    const float *bv = nullptr, *Wf = nullptr, *bfp = nullptr;
    for (int i = 0; i < n_in; ++i) {
        const float* p = (const float*)d_in[i];
        switch (in_sizes[i]) {
            case 16777216: X = p; break;
            case 4194304:  if (!c1) c1 = p; else c2 = p; break;
            case 4096:     bv = p; break;
            case 3:        Wf = p; break;
            case 1:        bfp = p; break;
            default: break;
        }
    }

    float* out_f = (float*)d_out;
    float* outVa = out_f;
    float* outX  = out_f + (size_t)N2 * D2;

    // d_ws (~24 MiB used <= proven 25 MiB)
    int* flags   = (int*)d_ws;
    int* flagCnt = (int*)((char*)d_ws + 128);
    char* C0 = (char*)d_ws + 1024;
    float*  sXF     = (float*) (C0);                 // 16 KiB
    float*  invnF   = (float*) (C0 + 16384);         // 16 KiB
    int*    tidx    = (int*)   (C0 + 32768);         // 48 KiB
    double* sXD     = (double*)(C0 + 81920);         // 32 KiB
    double* invnD   = (double*)(C0 + 114688);        // 32 KiB
    float*  partial = (float*) (C0 + 147456);        // 512 KiB
    float*  candV   = (float*) (C0 + 671744);        // 3 MiB
    int*    candI   = (int*)   (C0 + 3817472);       // 3 MiB
    int*    flagRow = (int*)   (C0 + 6963200);       // 4 KiB
    int*    flagCand= (int*)   (C0 + 6967296);       // 24 KiB
    unsigned short* Zh = (unsigned short*)(C0 + 8388608);   // 8 MiB
    unsigned short* Zl = (unsigned short*)(C0 + 16777216);  // 8 MiB

    // d_out upper half (outX region) scratch until the final memcpy:
    // c-splits 32 MiB + Vph 32 MiB; after mfmaS the c-split region is dead
    // and its first 8 MiB hosts Zx (f64 [FCAP][1024] = 8 MiB).
    char* up = (char*)outX;
    unsigned short* c1h = (unsigned short*)(up);
    unsigned short* c1l = (unsigned short*)(up + 8388608);
    unsigned short* c2h = (unsigned short*)(up + 16777216);
    unsigned short* c2l = (unsigned short*)(up + 25165824);
    unsigned short* Vph = (unsigned short*)(up + 33554432);  // 32 MiB
    double* Zx = (double*)(up);   // overlays dead c1h/c1l after mfmaS

    kDetect<<<1, 256, 0, stream>>>(c1, c2, flags, flagCnt);
    kSplit<<<4096, 256, 0, stream>>>(c1, c1h, c1l, N1 * D1 / 4);
    kSplit<<<4096, 256, 0, stream>>>(c2, c2h, c2l, N1 * D1 / 4);
    kSvec<<<N2, 256, 0, stream>>>(X, bv, sXF, sXD);

    dim3 gN(D2 / 128, N1 / 128);
    kNormMfma<<<gN, 256, 0, stream>>>(c1h, c1l, c2h, c2l, bv, flags,
                                      partial, Vph);
    kInv<<<16, 256, 0, stream>>>(partial, invnF, invnD);

    dim3 gZ(D1 / 128, N2 / 128);
    mfmaZ<<<gZ, 256, 0, stream>>>(X, c1h, c1l, c2h, c2l, flags, Zh, Zl);

    dim3 gS(N1 / 128, N2 / 128);
    mfmaS<<<gS, 256, 0, stream>>>(Zh, Zl, c1h, c1l, c2h, c2l,
                                  invnF, sXF, flags, candV, candI);

    kMergeCert<<<N2, 64, 0, stream>>>(candV, candI, tidx,
                                      flagCnt, flagRow, flagCand);

    dim3 gX(8, ZB);
    kZx<<<gX, 128, 0, stream>>>(flagCnt, flagRow, c1, c2, flags, X, Zx);
    kScore6<<<FCAP, 64, 0, stream>>>(flagCnt, flagRow, flagCand, Zx,
                                     c1, c2, flags, sXD, invnD, tidx);

    kGatherVa<<<N2, 256, 0, stream>>>(Vph, tidx, Wf, bfp, outVa);

    hipMemcpyAsync(outX, X, (size_t)N2 * D2 * sizeof(float),
                   hipMemcpyDeviceToDevice, stream);
}